// Round 1
// baseline (14975.266 us; speedup 1.0000x reference)
//
#include <hip/hip_runtime.h>
#include <hip/hip_bf16.h>

#define K_TAPS 27
#define DCH 64
#define BN_EPS 1e-5f

// ---------------------------------------------------------------------------
// Gather-GEMM-scatter sparse conv: one thread per (k, pair).
// out[pout[k,p], :] += feats[pin[k,p], :] @ W[k]   (C x 64)
// W reads are wave-uniform -> scalar loads; acc in VGPRs; scatter via HW f32 atomics.
// ---------------------------------------------------------------------------
template <int C>
__global__ __launch_bounds__(256)
void scatter_conv_kernel(const float* __restrict__ feats,
                         const float* __restrict__ W,
                         const int* __restrict__ pin,
                         const int* __restrict__ pout,
                         float* __restrict__ out,
                         int P)
{
    const int k = blockIdx.y;
    const int p = blockIdx.x * 256 + threadIdx.x;
    if (p >= P) return;

    const int irow = pin[(size_t)k * P + p];
    const int orow = pout[(size_t)k * P + p];
    const float* __restrict__ frow = feats + (size_t)irow * C;
    const float* __restrict__ Wk   = W + (size_t)k * C * DCH;

    float acc[DCH];
#pragma unroll
    for (int d = 0; d < DCH; ++d) acc[d] = 0.f;

#pragma unroll
    for (int c0 = 0; c0 < C; c0 += 16) {
        float f[16];
#pragma unroll
        for (int j = 0; j < 16; j += 4) {
            float4 v = *reinterpret_cast<const float4*>(frow + c0 + j);
            f[j + 0] = v.x; f[j + 1] = v.y; f[j + 2] = v.z; f[j + 3] = v.w;
        }
#pragma unroll
        for (int j = 0; j < 16; ++j) {
            const float fc = f[j];
#pragma unroll
            for (int d = 0; d < DCH; ++d)
                acc[d] = __builtin_fmaf(fc, Wk[(c0 + j) * DCH + d], acc[d]);
        }
    }

    float* __restrict__ op = out + (size_t)orow * DCH;
#pragma unroll
    for (int d = 0; d < DCH; ++d)
        unsafeAtomicAdd(op + d, acc[d]);
}

// ---------------------------------------------------------------------------
// BN statistics: per-channel sum and sumsq over rows -> stats[0:64]=sum,
// stats[64:128]=sumsq (atomically accumulated; caller zeroes stats).
// ---------------------------------------------------------------------------
__global__ __launch_bounds__(256)
void bn_stats_kernel(const float* __restrict__ x, int n_rows,
                     float* __restrict__ stats)
{
    const int d      = threadIdx.x & 63;
    const int rowOff = threadIdx.x >> 6;  // 0..3
    float s = 0.f, ss = 0.f;
    for (int r = blockIdx.x * 4 + rowOff; r < n_rows; r += gridDim.x * 4) {
        float v = x[(size_t)r * DCH + d];
        s += v;
        ss += v * v;
    }
    __shared__ float ls[256], lss[256];
    ls[threadIdx.x] = s;
    lss[threadIdx.x] = ss;
    __syncthreads();
    if (threadIdx.x < 64) {
        s  = ls[threadIdx.x] + ls[threadIdx.x + 64] + ls[threadIdx.x + 128] + ls[threadIdx.x + 192];
        ss = lss[threadIdx.x] + lss[threadIdx.x + 64] + lss[threadIdx.x + 128] + lss[threadIdx.x + 192];
        unsafeAtomicAdd(&stats[d], s);
        unsafeAtomicAdd(&stats[64 + d], ss);
    }
}

// ---------------------------------------------------------------------------
// In-place BN + ReLU: x = relu((x - m) * rsqrt(v+eps) * g + b)
// blockDim=256 and stride multiple of 64 => channel of element i is tid&63.
// ---------------------------------------------------------------------------
__global__ __launch_bounds__(256)
void bn_apply_kernel(float* __restrict__ x, int n_elem,
                     const float* __restrict__ stats,
                     const float* __restrict__ g,
                     const float* __restrict__ b,
                     float inv_n)
{
    const int d = threadIdx.x & 63;
    const float m   = stats[d] * inv_n;
    const float var = stats[64 + d] * inv_n - m * m;
    const float sc  = g[d] * rsqrtf(var + BN_EPS);
    const float sh  = b[d] - m * sc;
    for (int i = blockIdx.x * 256 + threadIdx.x; i < n_elem; i += gridDim.x * 256) {
        float v = x[i];
        x[i] = fmaxf(__builtin_fmaf(v, sc, sh), 0.f);
    }
}

// ---------------------------------------------------------------------------
// Final: out = x_net + relu(bn(y2)) ; y2 lives in `out` (in place).
// ---------------------------------------------------------------------------
__global__ __launch_bounds__(256)
void bn_final_kernel(float* __restrict__ y2, const float* __restrict__ xnet,
                     int n_elem,
                     const float* __restrict__ stats,
                     const float* __restrict__ g,
                     const float* __restrict__ b,
                     float inv_n)
{
    const int d = threadIdx.x & 63;
    const float m   = stats[d] * inv_n;
    const float var = stats[64 + d] * inv_n - m * m;
    const float sc  = g[d] * rsqrtf(var + BN_EPS);
    const float sh  = b[d] - m * sc;
    for (int i = blockIdx.x * 256 + threadIdx.x; i < n_elem; i += gridDim.x * 256) {
        float v = y2[i];
        y2[i] = xnet[i] + fmaxf(__builtin_fmaf(v, sc, sh), 0.f);
    }
}

extern "C" void kernel_launch(void* const* d_in, const int* in_sizes, int n_in,
                              void* d_out, int out_size, void* d_ws, size_t ws_size,
                              hipStream_t stream)
{
    const float* feats  = (const float*)d_in[0];
    const float* W_down = (const float*)d_in[1];
    const float* g0     = (const float*)d_in[2];
    const float* b0     = (const float*)d_in[3];
    const float* W1     = (const float*)d_in[4];
    const float* g1     = (const float*)d_in[5];
    const float* b1     = (const float*)d_in[6];
    const float* W2     = (const float*)d_in[7];
    const float* g2     = (const float*)d_in[8];
    const float* b2     = (const float*)d_in[9];
    const int* pdi      = (const int*)d_in[10];
    const int* pdo      = (const int*)d_in[11];
    const int* psi      = (const int*)d_in[12];
    const int* pso      = (const int*)d_in[13];

    const int P1    = in_sizes[10] / K_TAPS;
    const int P2    = in_sizes[12] / K_TAPS;
    const int n_out = out_size / DCH;
    const int n_elem = n_out * DCH;
    const float inv_n = 1.0f / (float)n_out;

    float* out  = (float*)d_out;
    float* ws0  = (float*)d_ws;                       // n_out*64 floats (x_net)
    float* stats = ws0 + (size_t)n_elem;              // 3 * 128 floats

    float* st0 = stats;
    float* st1 = stats + 128;
    float* st2 = stats + 256;

    // zero accumulation targets (deterministic across graph replays)
    hipMemsetAsync(out, 0, sizeof(float) * (size_t)n_elem, stream);
    hipMemsetAsync(stats, 0, sizeof(float) * 384, stream);

    const dim3 blk(256);
    const dim3 gridC1((P1 + 255) / 256, K_TAPS);
    const dim3 gridC2((P2 + 255) / 256, K_TAPS);
    const int statBlocks = 256;
    const int ewBlocks = 2048;

    // ---- DownBlock: y0 = conv(feats) -> d_out ; x0 = bnrelu(y0) in place ----
    scatter_conv_kernel<32><<<gridC1, blk, 0, stream>>>(feats, W_down, pdi, pdo, out, P1);
    bn_stats_kernel<<<statBlocks, blk, 0, stream>>>(out, n_out, st0);
    bn_apply_kernel<<<ewBlocks, blk, 0, stream>>>(out, n_elem, st0, g0, b0, inv_n);

    // ---- ResBlock conv1: y1 = conv(x0) -> ws0 ; x_net = bnrelu(y1) in place ----
    hipMemsetAsync(ws0, 0, sizeof(float) * (size_t)n_elem, stream);
    scatter_conv_kernel<64><<<gridC2, blk, 0, stream>>>(out, W1, psi, pso, ws0, P2);
    bn_stats_kernel<<<statBlocks, blk, 0, stream>>>(ws0, n_out, st1);
    bn_apply_kernel<<<ewBlocks, blk, 0, stream>>>(ws0, n_elem, st1, g1, b1, inv_n);

    // ---- ResBlock conv2: y2 = conv(x_net) -> d_out (x0 dead) ----
    hipMemsetAsync(out, 0, sizeof(float) * (size_t)n_elem, stream);
    scatter_conv_kernel<64><<<gridC2, blk, 0, stream>>>(ws0, W2, psi, pso, out, P2);
    bn_stats_kernel<<<statBlocks, blk, 0, stream>>>(out, n_out, st2);

    // ---- out = x_net + relu(bn(y2)) ----
    bn_final_kernel<<<ewBlocks, blk, 0, stream>>>(out, ws0, n_elem, st2, g2, b2, inv_n);
}

// Round 3
// 1936.865 us; speedup vs baseline: 7.7317x; 7.7317x over previous
//
#include <hip/hip_runtime.h>
#include <hip/hip_bf16.h>

#define K_TAPS 27
#define DCH 64
#define BN_EPS 1e-5f
#define SCAN_CHUNK 4096

// ---------------------------------------------------------------------------
// CSR build: histogram over buckets b = orow*27 + k
// ---------------------------------------------------------------------------
__global__ __launch_bounds__(256)
void hist_kernel(const int* __restrict__ pout, int P, int* __restrict__ counts)
{
    const int k = blockIdx.y;
    const int p = blockIdx.x * 256 + threadIdx.x;
    if (p < P) {
        const int r = pout[(size_t)k * P + p];
        atomicAdd(&counts[r * K_TAPS + k], 1);
    }
}

// pass 1: per-chunk sums
__global__ __launch_bounds__(256)
void scan_sum_kernel(const int* __restrict__ counts, int n, int* __restrict__ partials)
{
    __shared__ int sm[256];
    const int base = blockIdx.x * SCAN_CHUNK;
    int s = 0;
#pragma unroll
    for (int j = 0; j < 16; ++j) {
        const int i = base + j * 256 + threadIdx.x;
        if (i < n) s += counts[i];
    }
    sm[threadIdx.x] = s;
    __syncthreads();
    for (int off = 128; off > 0; off >>= 1) {
        if (threadIdx.x < off) sm[threadIdx.x] += sm[threadIdx.x + off];
        __syncthreads();
    }
    if (threadIdx.x == 0) partials[blockIdx.x] = sm[0];
}

// pass 2: exclusive scan of chunk partials in place (single block)
__global__ __launch_bounds__(512)
void scan_partials_kernel(int* __restrict__ partials, int n)
{
    __shared__ int sm[512];
    const int t = threadIdx.x;
    const int v = (t < n) ? partials[t] : 0;
    sm[t] = v;
    __syncthreads();
    for (int off = 1; off < 512; off <<= 1) {
        int tv = 0;
        if (t >= off) tv = sm[t - off];
        __syncthreads();
        if (t >= off) sm[t] += tv;
        __syncthreads();
    }
    if (t < n) partials[t] = sm[t] - v;  // exclusive
}

// pass 3: write exclusive prefix to S[b+1]; S[0] = 0
__global__ __launch_bounds__(256)
void scan_write_kernel(const int* __restrict__ counts, int n,
                       const int* __restrict__ chunkoff, int* __restrict__ S)
{
    __shared__ int sm[256];
    const int base = blockIdx.x * SCAN_CHUNK + threadIdx.x * 16;
    int v[16];
    int s = 0;
#pragma unroll
    for (int j = 0; j < 16; ++j) {
        const int i = base + j;
        v[j] = (i < n) ? counts[i] : 0;
        s += v[j];
    }
    sm[threadIdx.x] = s;
    __syncthreads();
    for (int off = 1; off < 256; off <<= 1) {
        int tv = 0;
        if (threadIdx.x >= off) tv = sm[threadIdx.x - off];
        __syncthreads();
        if (threadIdx.x >= off) sm[threadIdx.x] += tv;
        __syncthreads();
    }
    int run = chunkoff[blockIdx.x] + sm[threadIdx.x] - s;  // exclusive base
#pragma unroll
    for (int j = 0; j < 16; ++j) {
        const int i = base + j;
        if (i < n) S[i + 1] = run;
        run += v[j];
    }
    if (blockIdx.x == 0 && threadIdx.x == 0) S[0] = 0;
}

// fill: consume S[b+1] as cursor; after this, S[b]..S[b+1] = bucket b range
__global__ __launch_bounds__(256)
void fill_kernel(const int* __restrict__ pin, const int* __restrict__ pout, int P,
                 int* __restrict__ S, int* __restrict__ E)
{
    const int k = blockIdx.y;
    const int p = blockIdx.x * 256 + threadIdx.x;
    if (p < P) {
        const size_t i = (size_t)k * P + p;
        const int b = pout[i] * K_TAPS + k;
        const int pos = atomicAdd(&S[b + 1], 1);
        E[pos] = pin[i];
    }
}

// ---------------------------------------------------------------------------
// Output-stationary gather conv. Block = 256 (4 waves); each wave owns
// G/4 output rows; W[k] column (lane's channel) cached in VGPRs per k.
// Writes every output row exactly once. NO atomics.
// ---------------------------------------------------------------------------
template <int C, int G>
__global__ __launch_bounds__(256)
void gather_conv_kernel(const float* __restrict__ x,
                        const float* __restrict__ W,
                        const int* __restrict__ S,
                        const int* __restrict__ E,
                        float* __restrict__ y,
                        int n_out)
{
    const int lane = threadIdx.x & 63;
    const int wave = threadIdx.x >> 6;
    constexpr int RW = G / 4;
    const int r0 = blockIdx.x * G + wave * RW;

    float acc0[RW], acc1[RW];
#pragma unroll
    for (int i = 0; i < RW; ++i) { acc0[i] = 0.f; acc1[i] = 0.f; }

    for (int k = 0; k < K_TAPS; ++k) {
        // cache W[k][:, lane] in registers, reused across all rows' entries
        float wreg[C];
        const float* __restrict__ Wk = W + (size_t)k * C * DCH + lane;
#pragma unroll
        for (int c = 0; c < C; ++c) wreg[c] = Wk[(size_t)c * DCH];

#pragma unroll
        for (int ri = 0; ri < RW; ++ri) {
            const int r = r0 + ri;
            if (r < n_out) {
                const int b = r * K_TAPS + k;
                const int e0 = S[b];
                const int e1 = S[b + 1];
                for (int e = e0; e < e1; ++e) {
                    const int irow = __builtin_amdgcn_readfirstlane(E[e]);
                    const float* __restrict__ frow = x + (size_t)irow * C;
#pragma unroll
                    for (int c4 = 0; c4 < C; c4 += 4) {
                        const float4 f = *reinterpret_cast<const float4*>(frow + c4);
                        acc0[ri] = __builtin_fmaf(f.x, wreg[c4 + 0], acc0[ri]);
                        acc1[ri] = __builtin_fmaf(f.y, wreg[c4 + 1], acc1[ri]);
                        acc0[ri] = __builtin_fmaf(f.z, wreg[c4 + 2], acc0[ri]);
                        acc1[ri] = __builtin_fmaf(f.w, wreg[c4 + 3], acc1[ri]);
                    }
                }
            }
        }
    }
#pragma unroll
    for (int ri = 0; ri < RW; ++ri) {
        const int r = r0 + ri;
        if (r < n_out) y[(size_t)r * DCH + lane] = acc0[ri] + acc1[ri];
    }
}

// ---------------------------------------------------------------------------
// BN statistics: per-channel sum and sumsq (atomic-reduced into 128 floats)
// ---------------------------------------------------------------------------
__global__ __launch_bounds__(256)
void bn_stats_kernel(const float* __restrict__ x, int n_rows,
                     float* __restrict__ stats)
{
    const int d      = threadIdx.x & 63;
    const int rowOff = threadIdx.x >> 6;
    float s = 0.f, ss = 0.f;
    for (int r = blockIdx.x * 4 + rowOff; r < n_rows; r += gridDim.x * 4) {
        float v = x[(size_t)r * DCH + d];
        s += v;
        ss += v * v;
    }
    __shared__ float ls[256], lss[256];
    ls[threadIdx.x] = s;
    lss[threadIdx.x] = ss;
    __syncthreads();
    if (threadIdx.x < 64) {
        s  = ls[threadIdx.x] + ls[threadIdx.x + 64] + ls[threadIdx.x + 128] + ls[threadIdx.x + 192];
        ss = lss[threadIdx.x] + lss[threadIdx.x + 64] + lss[threadIdx.x + 128] + lss[threadIdx.x + 192];
        unsafeAtomicAdd(&stats[d], s);
        unsafeAtomicAdd(&stats[64 + d], ss);
    }
}

__global__ __launch_bounds__(256)
void bn_apply_kernel(float* __restrict__ x, int n_elem,
                     const float* __restrict__ stats,
                     const float* __restrict__ g,
                     const float* __restrict__ b,
                     float inv_n)
{
    const int d = threadIdx.x & 63;
    const float m   = stats[d] * inv_n;
    const float var = stats[64 + d] * inv_n - m * m;
    const float sc  = g[d] * rsqrtf(var + BN_EPS);
    const float sh  = b[d] - m * sc;
    for (int i = blockIdx.x * 256 + threadIdx.x; i < n_elem; i += gridDim.x * 256) {
        float v = x[i];
        x[i] = fmaxf(__builtin_fmaf(v, sc, sh), 0.f);
    }
}

__global__ __launch_bounds__(256)
void bn_final_kernel(float* __restrict__ y2, const float* __restrict__ xnet,
                     int n_elem,
                     const float* __restrict__ stats,
                     const float* __restrict__ g,
                     const float* __restrict__ b,
                     float inv_n)
{
    const int d = threadIdx.x & 63;
    const float m   = stats[d] * inv_n;
    const float var = stats[64 + d] * inv_n - m * m;
    const float sc  = g[d] * rsqrtf(var + BN_EPS);
    const float sh  = b[d] - m * sc;
    for (int i = blockIdx.x * 256 + threadIdx.x; i < n_elem; i += gridDim.x * 256) {
        float v = y2[i];
        y2[i] = xnet[i] + fmaxf(__builtin_fmaf(v, sc, sh), 0.f);
    }
}

extern "C" void kernel_launch(void* const* d_in, const int* in_sizes, int n_in,
                              void* d_out, int out_size, void* d_ws, size_t ws_size,
                              hipStream_t stream)
{
    const float* feats  = (const float*)d_in[0];
    const float* W_down = (const float*)d_in[1];
    const float* g0     = (const float*)d_in[2];
    const float* b0     = (const float*)d_in[3];
    const float* W1     = (const float*)d_in[4];
    const float* g1     = (const float*)d_in[5];
    const float* b1     = (const float*)d_in[6];
    const float* W2     = (const float*)d_in[7];
    const float* g2     = (const float*)d_in[8];
    const float* b2     = (const float*)d_in[9];
    const int* pdi      = (const int*)d_in[10];
    const int* pdo      = (const int*)d_in[11];
    const int* psi      = (const int*)d_in[12];
    const int* pso      = (const int*)d_in[13];

    const int P1     = in_sizes[10] / K_TAPS;
    const int P2     = in_sizes[12] / K_TAPS;
    const int M1     = in_sizes[10];
    const int n_out  = out_size / DCH;
    const int n_elem = n_out * DCH;
    const int NB     = n_out * K_TAPS;
    const float inv_n = 1.0f / (float)n_out;

    float* out = (float*)d_out;

    // ---- workspace layout (low watermark ~29 MB) ----
    // [0]            xnet : n_elem floats   -- live from conv2 on.
    //                counts (NB ints) overlays xnet during CSR builds (dead then)
    // [n_elem]       stats: 384 floats
    // [after stats]  CSR region R: S (NB+1 ints) + E (max(M1,M2) ints)
    //                holds down CSR for conv1, then REBUILT as subm CSR.
    // [after R]      partials: 1024 ints
    float* xnet  = (float*)d_ws;
    int*   counts = (int*)d_ws;
    float* stats = xnet + (size_t)n_elem;
    int* S = (int*)(stats + 384);
    int* E = S + (NB + 1);
    int* partials = E + M1;   // M1 >= M2, so this is past both CSR variants

    float* st0 = stats;
    float* st1 = stats + 128;
    float* st2 = stats + 256;

    const dim3 blk(256);
    const dim3 gridH1((P1 + 255) / 256, K_TAPS);
    const dim3 gridH2((P2 + 255) / 256, K_TAPS);
    const int nchunks = (NB + SCAN_CHUNK - 1) / SCAN_CHUNK;
    const int gatherBlocks = (n_out + 63) / 64;
    const int statBlocks = 256;
    const int ewBlocks = 2048;

    hipMemsetAsync(stats, 0, sizeof(float) * 384, stream);

    // ---- build down CSR ----
    hipMemsetAsync(counts, 0, sizeof(int) * (size_t)NB, stream);
    hist_kernel<<<gridH1, blk, 0, stream>>>(pdo, P1, counts);
    scan_sum_kernel<<<nchunks, blk, 0, stream>>>(counts, NB, partials);
    scan_partials_kernel<<<1, 512, 0, stream>>>(partials, nchunks);
    scan_write_kernel<<<nchunks, blk, 0, stream>>>(counts, NB, partials, S);
    fill_kernel<<<gridH1, blk, 0, stream>>>(pdi, pdo, P1, S, E);

    // ---- DownBlock: y0 = conv(feats) -> d_out ; x0 = bnrelu(y0) in place ----
    gather_conv_kernel<32, 64><<<gatherBlocks, blk, 0, stream>>>(feats, W_down, S, E, out, n_out);
    bn_stats_kernel<<<statBlocks, blk, 0, stream>>>(out, n_out, st0);
    bn_apply_kernel<<<ewBlocks, blk, 0, stream>>>(out, n_elem, st0, g0, b0, inv_n);

    // ---- rebuild CSR region as subm CSR (down CSR now dead) ----
    hipMemsetAsync(counts, 0, sizeof(int) * (size_t)NB, stream);
    hist_kernel<<<gridH2, blk, 0, stream>>>(pso, P2, counts);
    scan_sum_kernel<<<nchunks, blk, 0, stream>>>(counts, NB, partials);
    scan_partials_kernel<<<1, 512, 0, stream>>>(partials, nchunks);
    scan_write_kernel<<<nchunks, blk, 0, stream>>>(counts, NB, partials, S);
    fill_kernel<<<gridH2, blk, 0, stream>>>(psi, pso, P2, S, E);

    // ---- ResBlock conv1: y1 = conv(x0) -> xnet ; bnrelu in place ----
    gather_conv_kernel<64, 64><<<gatherBlocks, blk, 0, stream>>>(out, W1, S, E, xnet, n_out);
    bn_stats_kernel<<<statBlocks, blk, 0, stream>>>(xnet, n_out, st1);
    bn_apply_kernel<<<ewBlocks, blk, 0, stream>>>(xnet, n_elem, st1, g1, b1, inv_n);

    // ---- ResBlock conv2: y2 = conv(x_net) -> d_out ----
    gather_conv_kernel<64, 64><<<gatherBlocks, blk, 0, stream>>>(xnet, W2, S, E, out, n_out);
    bn_stats_kernel<<<statBlocks, blk, 0, stream>>>(out, n_out, st2);

    // ---- out = x_net + relu(bn(y2)) ----
    bn_final_kernel<<<ewBlocks, blk, 0, stream>>>(out, xnet, n_elem, st2, g2, b2, inv_n);
}

// Round 4
// 1258.313 us; speedup vs baseline: 11.9011x; 1.5393x over previous
//
#include <hip/hip_runtime.h>
#include <hip/hip_bf16.h>

#define K_TAPS 27
#define DCH 64
#define BN_EPS 1e-5f
#define SCAN_CHUNK 4096

// ---------------------------------------------------------------------------
// CSR build: histogram over buckets b = orow*27 + k
// ---------------------------------------------------------------------------
__global__ __launch_bounds__(256)
void hist_kernel(const int* __restrict__ pout, int P, int* __restrict__ counts)
{
    const int k = blockIdx.y;
    const int p = blockIdx.x * 256 + threadIdx.x;
    if (p < P) {
        const int r = pout[(size_t)k * P + p];
        atomicAdd(&counts[r * K_TAPS + k], 1);
    }
}

__global__ __launch_bounds__(256)
void scan_sum_kernel(const int* __restrict__ counts, int n, int* __restrict__ partials)
{
    __shared__ int sm[256];
    const int base = blockIdx.x * SCAN_CHUNK;
    int s = 0;
#pragma unroll
    for (int j = 0; j < 16; ++j) {
        const int i = base + j * 256 + threadIdx.x;
        if (i < n) s += counts[i];
    }
    sm[threadIdx.x] = s;
    __syncthreads();
    for (int off = 128; off > 0; off >>= 1) {
        if (threadIdx.x < off) sm[threadIdx.x] += sm[threadIdx.x + off];
        __syncthreads();
    }
    if (threadIdx.x == 0) partials[blockIdx.x] = sm[0];
}

__global__ __launch_bounds__(512)
void scan_partials_kernel(int* __restrict__ partials, int n)
{
    __shared__ int sm[512];
    const int t = threadIdx.x;
    const int v = (t < n) ? partials[t] : 0;
    sm[t] = v;
    __syncthreads();
    for (int off = 1; off < 512; off <<= 1) {
        int tv = 0;
        if (t >= off) tv = sm[t - off];
        __syncthreads();
        if (t >= off) sm[t] += tv;
        __syncthreads();
    }
    if (t < n) partials[t] = sm[t] - v;  // exclusive
}

__global__ __launch_bounds__(256)
void scan_write_kernel(const int* __restrict__ counts, int n,
                       const int* __restrict__ chunkoff, int* __restrict__ S)
{
    __shared__ int sm[256];
    const int base = blockIdx.x * SCAN_CHUNK + threadIdx.x * 16;
    int v[16];
    int s = 0;
#pragma unroll
    for (int j = 0; j < 16; ++j) {
        const int i = base + j;
        v[j] = (i < n) ? counts[i] : 0;
        s += v[j];
    }
    sm[threadIdx.x] = s;
    __syncthreads();
    for (int off = 1; off < 256; off <<= 1) {
        int tv = 0;
        if (threadIdx.x >= off) tv = sm[threadIdx.x - off];
        __syncthreads();
        if (threadIdx.x >= off) sm[threadIdx.x] += tv;
        __syncthreads();
    }
    int run = chunkoff[blockIdx.x] + sm[threadIdx.x] - s;  // exclusive base
#pragma unroll
    for (int j = 0; j < 16; ++j) {
        const int i = base + j;
        if (i < n) S[i + 1] = run;
        run += v[j];
    }
    if (blockIdx.x == 0 && threadIdx.x == 0) S[0] = 0;
}

__global__ __launch_bounds__(256)
void fill_kernel(const int* __restrict__ pin, const int* __restrict__ pout, int P,
                 int* __restrict__ S, int* __restrict__ E)
{
    const int k = blockIdx.y;
    const int p = blockIdx.x * 256 + threadIdx.x;
    if (p < P) {
        const size_t i = (size_t)k * P + p;
        const int b = pout[i] * K_TAPS + k;
        const int pos = atomicAdd(&S[b + 1], 1);
        E[pos] = pin[i];
    }
}

// ---------------------------------------------------------------------------
// Output-stationary gather conv, v2.
//  - RW rows per wave, 4 waves/block -> 4*RW rows/block.
//  - W[k][:,lane] kept RESIDENT in VGPRs (launch_bounds MINW sized so it fits).
//  - Wave's contiguous S-slice (27*RW+1 ints) staged once through LDS.
//  - No atomics; each output row written exactly once.
// ---------------------------------------------------------------------------
template <int C, int RW, int MINW>
__global__ __launch_bounds__(256, MINW)
void gather_conv_kernel(const float* __restrict__ x,
                        const float* __restrict__ W,
                        const int* __restrict__ S,
                        const int* __restrict__ E,
                        float* __restrict__ y,
                        int n_out)
{
    const int lane = threadIdx.x & 63;
    const int wave = threadIdx.x >> 6;
    const int r0 = blockIdx.x * (4 * RW) + wave * RW;
    constexpr int SN = K_TAPS * RW + 1;

    __shared__ int sS[4][SN];
    {
        const int base = r0 * K_TAPS;
        const int NBtot = n_out * K_TAPS;
        for (int i = lane; i < SN; i += 64) {
            int v = 0;
            if (r0 < n_out) {
                int gi = base + i;
                if (gi > NBtot) gi = NBtot;
                v = S[gi];
            }
            sS[wave][i] = v;
        }
    }
    __syncthreads();

    float wreg[C];
    float acc0[RW], acc1[RW];
#pragma unroll
    for (int i = 0; i < RW; ++i) { acc0[i] = 0.f; acc1[i] = 0.f; }

    for (int k = 0; k < K_TAPS; ++k) {
        const float* __restrict__ Wk = W + (size_t)k * C * DCH + lane;
#pragma unroll
        for (int c = 0; c < C; ++c) wreg[c] = Wk[(size_t)c * DCH];

#pragma unroll
        for (int ri = 0; ri < RW; ++ri) {
            const int e0 = sS[wave][ri * K_TAPS + k];
            const int e1 = sS[wave][ri * K_TAPS + k + 1];
            for (int e = e0; e < e1; ++e) {
                const int irow = __builtin_amdgcn_readfirstlane(E[e]);
                const float* __restrict__ frow = x + (size_t)irow * C;
#pragma unroll
                for (int c4 = 0; c4 < C; c4 += 4) {
                    const float4 f = *reinterpret_cast<const float4*>(frow + c4);
                    acc0[ri] = __builtin_fmaf(f.x, wreg[c4 + 0], acc0[ri]);
                    acc1[ri] = __builtin_fmaf(f.y, wreg[c4 + 1], acc1[ri]);
                    acc0[ri] = __builtin_fmaf(f.z, wreg[c4 + 2], acc0[ri]);
                    acc1[ri] = __builtin_fmaf(f.w, wreg[c4 + 3], acc1[ri]);
                }
            }
        }
    }

#pragma unroll
    for (int ri = 0; ri < RW; ++ri) {
        const int r = r0 + ri;
        if (r < n_out) y[(size_t)r * DCH + lane] = acc0[ri] + acc1[ri];
    }
}

// ---------------------------------------------------------------------------
// BN statistics: per-channel sum and sumsq (atomic-reduced into 128 floats)
// ---------------------------------------------------------------------------
__global__ __launch_bounds__(256)
void bn_stats_kernel(const float* __restrict__ x, int n_rows,
                     float* __restrict__ stats)
{
    const int d      = threadIdx.x & 63;
    const int rowOff = threadIdx.x >> 6;
    float s = 0.f, ss = 0.f;
    for (int r = blockIdx.x * 4 + rowOff; r < n_rows; r += gridDim.x * 4) {
        float v = x[(size_t)r * DCH + d];
        s += v;
        ss += v * v;
    }
    __shared__ float ls[256], lss[256];
    ls[threadIdx.x] = s;
    lss[threadIdx.x] = ss;
    __syncthreads();
    if (threadIdx.x < 64) {
        s  = ls[threadIdx.x] + ls[threadIdx.x + 64] + ls[threadIdx.x + 128] + ls[threadIdx.x + 192];
        ss = lss[threadIdx.x] + lss[threadIdx.x + 64] + lss[threadIdx.x + 128] + lss[threadIdx.x + 192];
        unsafeAtomicAdd(&stats[d], s);
        unsafeAtomicAdd(&stats[64 + d], ss);
    }
}

__global__ __launch_bounds__(256)
void bn_apply_kernel(float* __restrict__ x, int n_elem,
                     const float* __restrict__ stats,
                     const float* __restrict__ g,
                     const float* __restrict__ b,
                     float inv_n)
{
    const int d = threadIdx.x & 63;
    const float m   = stats[d] * inv_n;
    const float var = stats[64 + d] * inv_n - m * m;
    const float sc  = g[d] * rsqrtf(var + BN_EPS);
    const float sh  = b[d] - m * sc;
    for (int i = blockIdx.x * 256 + threadIdx.x; i < n_elem; i += gridDim.x * 256) {
        float v = x[i];
        x[i] = fmaxf(__builtin_fmaf(v, sc, sh), 0.f);
    }
}

__global__ __launch_bounds__(256)
void bn_final_kernel(float* __restrict__ y2, const float* __restrict__ xnet,
                     int n_elem,
                     const float* __restrict__ stats,
                     const float* __restrict__ g,
                     const float* __restrict__ b,
                     float inv_n)
{
    const int d = threadIdx.x & 63;
    const float m   = stats[d] * inv_n;
    const float var = stats[64 + d] * inv_n - m * m;
    const float sc  = g[d] * rsqrtf(var + BN_EPS);
    const float sh  = b[d] - m * sc;
    for (int i = blockIdx.x * 256 + threadIdx.x; i < n_elem; i += gridDim.x * 256) {
        float v = y2[i];
        y2[i] = xnet[i] + fmaxf(__builtin_fmaf(v, sc, sh), 0.f);
    }
}

extern "C" void kernel_launch(void* const* d_in, const int* in_sizes, int n_in,
                              void* d_out, int out_size, void* d_ws, size_t ws_size,
                              hipStream_t stream)
{
    const float* feats  = (const float*)d_in[0];
    const float* W_down = (const float*)d_in[1];
    const float* g0     = (const float*)d_in[2];
    const float* b0     = (const float*)d_in[3];
    const float* W1     = (const float*)d_in[4];
    const float* g1     = (const float*)d_in[5];
    const float* b1     = (const float*)d_in[6];
    const float* W2     = (const float*)d_in[7];
    const float* g2     = (const float*)d_in[8];
    const float* b2     = (const float*)d_in[9];
    const int* pdi      = (const int*)d_in[10];
    const int* pdo      = (const int*)d_in[11];
    const int* psi      = (const int*)d_in[12];
    const int* pso      = (const int*)d_in[13];

    const int P1     = in_sizes[10] / K_TAPS;
    const int P2     = in_sizes[12] / K_TAPS;
    const int M1     = in_sizes[10];
    const int n_out  = out_size / DCH;
    const int n_elem = n_out * DCH;
    const int NB     = n_out * K_TAPS;
    const float inv_n = 1.0f / (float)n_out;

    float* out = (float*)d_out;

    // ---- workspace layout (~29 MB) ----
    float* xnet  = (float*)d_ws;
    int*   counts = (int*)d_ws;          // overlays xnet during CSR builds
    float* stats = xnet + (size_t)n_elem;
    int* S = (int*)(stats + 384);
    int* E = S + (NB + 1);
    int* partials = E + M1;              // M1 >= M2

    float* st0 = stats;
    float* st1 = stats + 128;
    float* st2 = stats + 256;

    const dim3 blk(256);
    const dim3 gridH1((P1 + 255) / 256, K_TAPS);
    const dim3 gridH2((P2 + 255) / 256, K_TAPS);
    const int nchunks = (NB + SCAN_CHUNK - 1) / SCAN_CHUNK;
    const int statBlocks = 256;
    const int ewBlocks = 2048;

    // down conv: C=32, RW=4 (16 rows/block), MINW=4 (<=64 VGPR, 8 waves/SIMD)
    constexpr int RW_DN = 4;
    const int gatherBlocksDn = (n_out + 4 * RW_DN - 1) / (4 * RW_DN);
    // subm conv: C=64, RW=8 (32 rows/block), MINW=2 (<=128 VGPR, wreg resident)
    constexpr int RW_SM = 8;
    const int gatherBlocksSm = (n_out + 4 * RW_SM - 1) / (4 * RW_SM);

    hipMemsetAsync(stats, 0, sizeof(float) * 384, stream);

    // ---- build down CSR ----
    hipMemsetAsync(counts, 0, sizeof(int) * (size_t)NB, stream);
    hist_kernel<<<gridH1, blk, 0, stream>>>(pdo, P1, counts);
    scan_sum_kernel<<<nchunks, blk, 0, stream>>>(counts, NB, partials);
    scan_partials_kernel<<<1, 512, 0, stream>>>(partials, nchunks);
    scan_write_kernel<<<nchunks, blk, 0, stream>>>(counts, NB, partials, S);
    fill_kernel<<<gridH1, blk, 0, stream>>>(pdi, pdo, P1, S, E);

    // ---- DownBlock: y0 = conv(feats) -> d_out ; x0 = bnrelu(y0) in place ----
    gather_conv_kernel<32, RW_DN, 4><<<gatherBlocksDn, blk, 0, stream>>>(feats, W_down, S, E, out, n_out);
    bn_stats_kernel<<<statBlocks, blk, 0, stream>>>(out, n_out, st0);
    bn_apply_kernel<<<ewBlocks, blk, 0, stream>>>(out, n_elem, st0, g0, b0, inv_n);

    // ---- rebuild CSR region as subm CSR (down CSR now dead) ----
    hipMemsetAsync(counts, 0, sizeof(int) * (size_t)NB, stream);
    hist_kernel<<<gridH2, blk, 0, stream>>>(pso, P2, counts);
    scan_sum_kernel<<<nchunks, blk, 0, stream>>>(counts, NB, partials);
    scan_partials_kernel<<<1, 512, 0, stream>>>(partials, nchunks);
    scan_write_kernel<<<nchunks, blk, 0, stream>>>(counts, NB, partials, S);
    fill_kernel<<<gridH2, blk, 0, stream>>>(psi, pso, P2, S, E);

    // ---- ResBlock conv1: y1 = conv(x0) -> xnet ; bnrelu in place ----
    gather_conv_kernel<64, RW_SM, 2><<<gatherBlocksSm, blk, 0, stream>>>(out, W1, S, E, xnet, n_out);
    bn_stats_kernel<<<statBlocks, blk, 0, stream>>>(xnet, n_out, st1);
    bn_apply_kernel<<<ewBlocks, blk, 0, stream>>>(xnet, n_elem, st1, g1, b1, inv_n);

    // ---- ResBlock conv2: y2 = conv(x_net) -> d_out ----
    gather_conv_kernel<64, RW_SM, 2><<<gatherBlocksSm, blk, 0, stream>>>(xnet, W2, S, E, out, n_out);
    bn_stats_kernel<<<statBlocks, blk, 0, stream>>>(out, n_out, st2);

    // ---- out = x_net + relu(bn(y2)) ----
    bn_final_kernel<<<ewBlocks, blk, 0, stream>>>(out, xnet, n_elem, st2, g2, b2, inv_n);
}